// Round 1
// baseline (2263.708 us; speedup 1.0000x reference)
//
#include <hip/hip_runtime.h>
#include <hip/hip_cooperative_groups.h>

namespace cg = cooperative_groups;

#define NN   2048
#define FF   512
#define CC   128
#define WROW 2560            // FF + NN
#define INFV 1.0e9f

__device__ __forceinline__ unsigned enc(float x) { return __float_as_uint(x); }
__device__ __forceinline__ float dec(unsigned x) { return __uint_as_float(x); }

// One cooperative kernel:
//  - Bellman-Ford sweeps until bitwise convergence (triple-buffered, atomicMin
//    on uint-encoded nonneg floats), folding each distance column into the
//    output accumulator (2 out elements per thread, kept in registers).
//  - Tail columns (post-convergence, all equal d_final) folded via a suffix
//    sum of W's distance columns.
//  - Epilogue: embedding dot (512) + bias, float2 store.
__global__ __launch_bounds__(256, 2)
void bf_gnn_kernel(const float* __restrict__ adj,
                   const float* __restrict__ emb,
                   const float* __restrict__ W,
                   const float* __restrict__ bias,
                   const int*   __restrict__ srcp,
                   float*       __restrict__ out,
                   unsigned*    __restrict__ ws_u,
                   int out_size)
{
    cg::grid_group grid = cg::this_grid();
    const int t = blockIdx.x * blockDim.x + threadIdx.x;   // 0..131071 (512*256)
    const int src = *srcp;

    unsigned* buf0  = ws_u;
    unsigned* buf1  = ws_u + NN;
    unsigned* buf2  = ws_u + 2 * NN;
    unsigned* flags = ws_u + 3 * NN;                 // indices 0..2048
    float*    parts = (float*)(ws_u + 3 * NN + 2064);
    float*    Sarr  = parts + NN;
    volatile unsigned* flagsv = flags;

    unsigned* bufs[3] = { buf0, buf1, buf2 };

    // ---- init (deterministic each launch; ws not re-poisoned by harness) ----
    if (t < NN) {
        buf0[t] = enc(t == src ? 0.0f : INFV);
        buf1[t] = 0xFFFFFFFFu;
        buf2[t] = 0xFFFFFFFFu;
    }
    if (t <= NN) flags[t] = 0u;

    // accumulator mapping: elements e0=2t, e0+1 -> v = e0>>7, c = e0&127 (even)
    const int e0 = 2 * t;
    const int v  = e0 >> 7;
    const int c0 = e0 & 127;
    const float initd = (v == src) ? 0.0f : INFV;
    // column 0 of distances = init vector
    float acc0 = initd * W[(size_t)c0 * WROW + FF];
    float acc1 = initd * W[(size_t)(c0 + 1) * WROW + FF];

    grid.sync();

    // phase-A mapping: v-col = t & 2047, u-chunk = t >> 11 (64 chunks x 32 u)
    const int chunk = t >> 11;
    const int vA    = t & (NN - 1);
    const int u0    = chunk * 32;

    int kconv = -1;
    const unsigned* finalBuf = nullptr;
    int has_neg = 0;

    for (int s = 1; s <= NN; ++s) {
        const unsigned* cur   = bufs[(s - 1) % 3];
        unsigned*       nb    = bufs[s % 3];
        unsigned*       spare = bufs[(s + 1) % 3];

        // convergence detected from previous sweep's flag (post-sync => visible)
        if (s >= 2 && flagsv[s - 1] == 0u) { kconv = s - 1; finalBuf = cur; break; }

        // ---- phase A: nb[v] = min(cur[v], min_u cur[u] + adj[u][v]) ----
        {
            float m = (chunk == 0) ? dec(cur[vA]) : 4.0e9f;
            const float* arow = adj + (size_t)u0 * NN + vA;
            #pragma unroll 8
            for (int i = 0; i < 32; ++i) {
                float du = dec(cur[u0 + i]);
                m = fminf(m, du + arow[(size_t)i * NN]);
            }
            atomicMin(&nb[vA], enc(m));   // nonneg floats: uint order == value order
        }
        grid.sync();

        // ---- phase B: convergence flag, accumulate column s, reset spare ----
        if (t < NN) {
            unsigned nv = nb[t];
            bool changed = (nv != cur[t]);
            unsigned long long b = __ballot(changed);
            if ((threadIdx.x & 63) == 0 && b) atomicOr(&flags[s], 1u);
            if (s < NN) spare[t] = 0xFFFFFFFFu;
        }
        if (s < NN) {   // s == NN is only the has_negative_cycle probe
            float dv = dec(nb[v]);
            acc0 = fmaf(dv, W[(size_t)c0 * WROW + FF + s], acc0);
            acc1 = fmaf(dv, W[(size_t)(c0 + 1) * WROW + FF + s], acc1);
        }
        grid.sync();
    }

    if (kconv < 0) {
        // ran all NN sweeps: sweep NN was the extra relaxation probe
        has_neg = (flagsv[NN] != 0u) ? 1 : 0;
    } else if (kconv < NN - 1) {
        // columns kconv+1 .. NN-1 all equal final distances:
        // acc += d_final[v] * sum_{i=kconv+1}^{NN-1} W[c, FF+i]
        if (t < NN) {
            int c = t >> 4, part = t & 15;
            float ssum = 0.0f;
            for (int i = kconv + 1 + part; i <= NN - 1; i += 16)
                ssum += W[(size_t)c * WROW + FF + i];
            parts[t] = ssum;
        }
        grid.sync();
        if (t < CC) {
            float ssum = 0.0f;
            #pragma unroll
            for (int p = 0; p < 16; ++p) ssum += parts[t * 16 + p];
            Sarr[t] = ssum;
        }
        grid.sync();
        float dv = dec(finalBuf[v]);
        acc0 = fmaf(dv, Sarr[c0],     acc0);
        acc1 = fmaf(dv, Sarr[c0 + 1], acc1);
    }

    // ---- epilogue: embedding dot (length 512) + bias, store ----
    {
        const float4* e4 = (const float4*)(emb + (size_t)v * FF);
        const float4* w0 = (const float4*)(W + (size_t)c0 * WROW);
        const float4* w1 = (const float4*)(W + (size_t)(c0 + 1) * WROW);
        float s0 = 0.0f, s1 = 0.0f;
        #pragma unroll 4
        for (int i = 0; i < FF / 4; ++i) {
            float4 a = e4[i], b0 = w0[i], b1 = w1[i];
            s0 += a.x * b0.x + a.y * b0.y + a.z * b0.z + a.w * b0.w;
            s1 += a.x * b1.x + a.y * b1.y + a.z * b1.z + a.w * b1.w;
        }
        acc0 += s0 + bias[c0];
        acc1 += s1 + bias[c0 + 1];
        *(float2*)(out + e0) = make_float2(acc0, acc1);
    }
    if (t == 0 && out_size > NN * CC) out[NN * CC] = has_neg ? 1.0f : 0.0f;
}

extern "C" void kernel_launch(void* const* d_in, const int* in_sizes, int n_in,
                              void* d_out, int out_size, void* d_ws, size_t ws_size,
                              hipStream_t stream) {
    const float* adj  = (const float*)d_in[0];
    const float* emb  = (const float*)d_in[1];
    const float* W    = (const float*)d_in[2];
    const float* bias = (const float*)d_in[3];
    const int*   srcp = (const int*)d_in[4];
    float* out = (float*)d_out;
    unsigned* ws = (unsigned*)d_ws;
    int osz = out_size;

    void* args[] = { (void*)&adj, (void*)&emb, (void*)&W, (void*)&bias,
                     (void*)&srcp, (void*)&out, (void*)&ws, (void*)&osz };
    hipLaunchCooperativeKernel((const void*)bf_gnn_kernel,
                               dim3(512), dim3(256), args, 0, stream);
}

// Round 2
// 460.741 us; speedup vs baseline: 4.9132x; 4.9132x over previous
//
#include <hip/hip_runtime.h>
#include <hip/hip_cooperative_groups.h>

namespace cg = cooperative_groups;

#define NN   2048
#define FF   512
#define CC   128
#define WROW 2560
#define INFV 1.0e9f
#define NB   64
#define NT   1024

#define AL(p)   __hip_atomic_load((p), __ATOMIC_RELAXED, __HIP_MEMORY_SCOPE_AGENT)
#define AS(p,v) __hip_atomic_store((p), (v), __ATOMIC_RELAXED, __HIP_MEMORY_SCOPE_AGENT)

struct WS {
    float    D[2][NN];        // dist ping-pong
    unsigned FL[2][NN];       // frontier lists ping-pong
    unsigned fcnt[NN + 4];    // per-sweep frontier counts (no reuse -> no races)
    unsigned arrive[NN + 4];  // per-sweep barrier counters (zeroed each launch)
    unsigned hasneg;
};

// Lightweight grid barrier: per-sweep dedicated counter, AGENT-scope atomics.
// All cross-block data is written with sc1 (write-through-to-L3) stores, so a
// vmcnt drain before the arrive-increment is the only fence needed.
__device__ __forceinline__ void gbar(unsigned* ctr) {
    __syncthreads();
    if (threadIdx.x == 0) {
        asm volatile("s_waitcnt vmcnt(0)" ::: "memory");
        __hip_atomic_fetch_add(ctr, 1u, __ATOMIC_RELAXED, __HIP_MEMORY_SCOPE_AGENT);
        while (AL(ctr) < NB) __builtin_amdgcn_s_sleep(2);
    }
    __syncthreads();
}

// Frontier-based Bellman-Ford (bitwise-identical columns to dense sweeps),
// folding each column into register accumulators; tail columns via suffix sums.
// 64 blocks x 1024 threads; block b owns output rows v in [32b, 32b+32).
__global__ __launch_bounds__(NT, 1)
void bf_gnn_sweep(const float* __restrict__ adj,
                  const float* __restrict__ emb,
                  const float* __restrict__ W,
                  const float* __restrict__ bias,
                  const int*   __restrict__ srcp,
                  float*       __restrict__ out,
                  WS* ws, int out_size)
{
    const int tid = threadIdx.x;
    const int b   = blockIdx.x;
    const int t   = b * NT + tid;
    const int src = *srcp;

    __shared__ float2   fr[NN];        // frontier (u, dist[u]) pairs
    __shared__ float    red[16][32];   // per-wave partial mins
    __shared__ float    dcol[32];      // this sweep's dist for owned v slice
    __shared__ float    sufp[CC][8];
    __shared__ float    Suf[CC];
    __shared__ unsigned s_fc;

    // ---- init ws (replay-safe: everything rewritten every launch) ----
    for (int i = t; i < NN; i += NB * NT)
        AS(&ws->D[0][i], (i == src) ? 0.0f : INFV);
    for (int i = t; i < NN + 4; i += NB * NT) {
        AS(&ws->fcnt[i], (i == 1) ? 1u : 0u);
        AS(&ws->arrive[i], 0u);
    }
    if (t == 0) { AS(&ws->FL[1][0], (unsigned)src); AS(&ws->hasneg, 0u); }

    const int vloc = tid & 31;        // owned-v lane (owners are tid<32)
    const int grp  = tid >> 5;        // 32 u-groups
    const int vb   = b * 32;
    const int v    = vb + vloc;
    const float* colp = adj + v;

    // accumulator mapping: out elem e0 = 4t -> v_acc = vb + (tid>>5), c0 = (4t)&127
    const int c0   = (4 * tid) & 127;
    const int vacc = tid >> 5;
    float dprev = (tid < 32) ? ((v == src) ? 0.0f : INFV) : 0.0f;

    float acc0, acc1, acc2, acc3;
    {
        const float d0 = ((vb + vacc) == src) ? 0.0f : INFV;   // column 0 = init
        const float* wr = W + FF;
        acc0 = d0 * wr[(size_t)c0 * WROW];
        acc1 = d0 * wr[(size_t)(c0 + 1) * WROW];
        acc2 = d0 * wr[(size_t)(c0 + 2) * WROW];
        acc3 = d0 * wr[(size_t)(c0 + 3) * WROW];
    }

    cg::this_grid().sync();   // one heavy sync: publishes init + cleans barriers

    int sbreak = -1;
    int s;
    for (s = 1; s <= NN - 1; ++s) {
        if (tid == 0) s_fc = AL(&ws->fcnt[s]);
        __syncthreads();
        const int fc = (int)s_fc;
        if (fc == 0) { sbreak = s; break; }   // dist_{s-1} is final

        // stage frontier (u, dist[u]) into LDS (sc1 loads: cross-XCD coherent)
        unsigned* FLc = ws->FL[s & 1];
        float*    Dp  = ws->D[(s - 1) & 1];
        for (int j = tid; j < fc; j += NT) {
            unsigned u = AL(&FLc[j]);
            fr[j] = make_float2(__uint_as_float(u), AL(&Dp[u]));
        }
        __syncthreads();

        // relax owned columns over the frontier (adj reads: normal cached, L2-resident)
        float m = 4.0e9f;
        #pragma unroll 4
        for (int j = grp; j < fc; j += 32) {
            float2 r = fr[j];
            unsigned u = __float_as_uint(r.x);
            m = fminf(m, r.y + colp[u * NN]);
        }
        m = fminf(m, __shfl_xor(m, 32, 64));
        if ((tid & 63) < 32) red[tid >> 6][vloc] = m;
        __syncthreads();

        if (tid < 32) {
            float mm = red[0][tid];
            #pragma unroll
            for (int w = 1; w < 16; ++w) mm = fminf(mm, red[w][tid]);
            float newv = fminf(dprev, mm);
            AS(&ws->D[s & 1][v], newv);
            bool changed = (newv != dprev);
            dprev = newv;
            dcol[tid] = newv;
            unsigned long long mask = __ballot(changed);
            int cnt = __popcll(mask);
            unsigned base = 0;
            if (tid == 0 && cnt)
                base = __hip_atomic_fetch_add(&ws->fcnt[s + 1], (unsigned)cnt,
                                              __ATOMIC_RELAXED, __HIP_MEMORY_SCOPE_AGENT);
            base = (unsigned)__shfl((int)base, 0, 64);
            if (changed) {
                int off = __popcll(mask & ((1ull << tid) - 1ull));
                AS(&ws->FL[(s + 1) & 1][base + off], (unsigned)v);
            }
        }
        __syncthreads();

        // fold column s (W reads: read-only, normal caches)
        {
            float dv = dcol[vacc];
            const float* wr = W + FF + s;
            acc0 = fmaf(dv, wr[(size_t)c0 * WROW], acc0);
            acc1 = fmaf(dv, wr[(size_t)(c0 + 1) * WROW], acc1);
            acc2 = fmaf(dv, wr[(size_t)(c0 + 2) * WROW], acc2);
            acc3 = fmaf(dv, wr[(size_t)(c0 + 3) * WROW], acc3);
        }
        gbar(&ws->arrive[s]);
    }

    unsigned hneg = 0;
    if (sbreak < 0) {
        // all NN-1 sweeps ran: negative-cycle probe (extra relaxation)
        if (tid == 0) s_fc = AL(&ws->fcnt[NN]);
        __syncthreads();
        const int fc = (int)s_fc;
        if (fc > 0) {
            unsigned* FLc = ws->FL[NN & 1];
            float*    Dp  = ws->D[(NN - 1) & 1];
            for (int j = tid; j < fc; j += NT) {
                unsigned u = AL(&FLc[j]);
                fr[j] = make_float2(__uint_as_float(u), AL(&Dp[u]));
            }
            __syncthreads();
            float m = 4.0e9f;
            for (int j = grp; j < fc; j += 32) {
                float2 r = fr[j];
                m = fminf(m, r.y + colp[__float_as_uint(r.x) * NN]);
            }
            m = fminf(m, __shfl_xor(m, 32, 64));
            if ((tid & 63) < 32) red[tid >> 6][vloc] = m;
            __syncthreads();
            if (tid < 32) {
                float mm = red[0][tid];
                #pragma unroll
                for (int w = 1; w < 16; ++w) mm = fminf(mm, red[w][tid]);
                if (fminf(dprev, mm) < dprev) AS(&ws->hasneg, 1u);
            }
            gbar(&ws->arrive[NN]);
            hneg = AL(&ws->hasneg);
        }
    } else {
        // tail: columns sbreak..NN-1 all equal final dist -> suffix sums of W
        const int c = tid >> 3, part = tid & 7;
        float ssum = 0.0f;
        for (int i = sbreak + part; i <= NN - 1; i += 8)
            ssum += W[(size_t)c * WROW + FF + i];
        sufp[c][part] = ssum;
        __syncthreads();
        if (tid < CC) {
            float x = 0.0f;
            #pragma unroll
            for (int p = 0; p < 8; ++p) x += sufp[tid][p];
            Suf[tid] = x;
        }
        __syncthreads();
        float dv = dcol[vacc];
        acc0 = fmaf(dv, Suf[c0],     acc0);
        acc1 = fmaf(dv, Suf[c0 + 1], acc1);
        acc2 = fmaf(dv, Suf[c0 + 2], acc2);
        acc3 = fmaf(dv, Suf[c0 + 3], acc3);
    }

    // ---- epilogue: embedding dot (512) + bias ----
    {
        const float4* e4 = (const float4*)(emb + (size_t)(vb + vacc) * FF);
        const float4* w0 = (const float4*)(W + (size_t)c0 * WROW);
        const float4* w1 = (const float4*)(W + (size_t)(c0 + 1) * WROW);
        const float4* w2 = (const float4*)(W + (size_t)(c0 + 2) * WROW);
        const float4* w3 = (const float4*)(W + (size_t)(c0 + 3) * WROW);
        float s0 = 0, s1 = 0, s2 = 0, s3 = 0;
        #pragma unroll 4
        for (int i = 0; i < FF / 4; ++i) {
            float4 a = e4[i];
            float4 x0 = w0[i], x1 = w1[i], x2 = w2[i], x3 = w3[i];
            s0 += a.x * x0.x + a.y * x0.y + a.z * x0.z + a.w * x0.w;
            s1 += a.x * x1.x + a.y * x1.y + a.z * x1.z + a.w * x1.w;
            s2 += a.x * x2.x + a.y * x2.y + a.z * x2.z + a.w * x2.w;
            s3 += a.x * x3.x + a.y * x3.y + a.z * x3.z + a.w * x3.w;
        }
        float4 o;
        o.x = acc0 + s0 + bias[c0];
        o.y = acc1 + s1 + bias[c0 + 1];
        o.z = acc2 + s2 + bias[c0 + 2];
        o.w = acc3 + s3 + bias[c0 + 3];
        *(float4*)(out + (size_t)4 * t) = o;
    }
    if (t == 0 && out_size > NN * CC) out[NN * CC] = hneg ? 1.0f : 0.0f;
}

extern "C" void kernel_launch(void* const* d_in, const int* in_sizes, int n_in,
                              void* d_out, int out_size, void* d_ws, size_t ws_size,
                              hipStream_t stream) {
    const float* adj  = (const float*)d_in[0];
    const float* emb  = (const float*)d_in[1];
    const float* W    = (const float*)d_in[2];
    const float* bias = (const float*)d_in[3];
    const int*   srcp = (const int*)d_in[4];
    float* out = (float*)d_out;
    WS* ws = (WS*)d_ws;
    int osz = out_size;

    void* args[] = { (void*)&adj, (void*)&emb, (void*)&W, (void*)&bias,
                     (void*)&srcp, (void*)&out, (void*)&ws, (void*)&osz };
    hipLaunchCooperativeKernel((const void*)bf_gnn_sweep,
                               dim3(NB), dim3(NT), args, 0, stream);
}